// Round 13
// baseline (224.670 us; speedup 1.0000x reference)
//
#include <hip/hip_runtime.h>

// VQ nearest-codebook argmin — fp16 MFMA pass-1 + block-per-row rescore.
//
// Pass 1 (validated r8-r11): G ≈ z16 . fp16(1024 e) / 1024, one f16 MFMA pass.
//   Rows with top-2 gap <= TAU=1.6e-4 -> list.
// Pass 2: ONE 256-THREAD BLOCK per flagged row. fp16 dot2 scan of all 1024
//   codes (4 lanes/code, 64 dims/lane, 2-deep shuffle), candidates =
//   v <= bv + WIN=1.2e-4. Then LOCKED numpy-fp32 recipe (rounds 3-11,
//   absmax 0) per candidate: s1,s2 numpy-pairwise fp32 sums of squares;
//   G exact-fp64 (order-free) -> fl32(2G); d = fl32(fl32(s1-2G)+s2);
//   argmin, first-index tie-break.
// r13 fix vs r12: e-fragment load was 32 halfs indexed as 64 (OOB ext_vector
//   components -> garbage scan). Now loads all 8 f16x8 with static extraction.

#define DDIM 256
#define KCODES 1024
#define TAU 1.6e-4f
#define WIN 1.2e-4f
#define LISTCAP 16384
#define CANDCAP 16
#define P2GRID 2048

typedef __attribute__((ext_vector_type(8))) _Float16 f16x8;
typedef __attribute__((ext_vector_type(2))) _Float16 h2;
typedef __attribute__((ext_vector_type(4))) float f32x4;
typedef __attribute__((ext_vector_type(8))) unsigned short u16x8;

// ---------- locked numerics helper (rounds 3-11, do not touch) ----------
__device__ __forceinline__ float block128_sq(const float* __restrict__ a)
{
#pragma clang fp contract(off)
    float r[8];
    #pragma unroll
    for (int j = 0; j < 8; ++j) { float v = a[j]; r[j] = v * v; }
    #pragma unroll
    for (int i = 8; i < 128; i += 8) {
        #pragma unroll
        for (int j = 0; j < 8; ++j) { float v = a[i + j]; r[j] = r[j] + v * v; }
    }
    return ((r[0] + r[1]) + (r[2] + r[3])) + ((r[4] + r[5]) + (r[6] + r[7]));
}

// ---- prep: e16 = fp16(1024*e), s2 pairwise, count reset (r9-validated) ----
__global__ __launch_bounds__(256) void vq_prep(
    const float* __restrict__ emb, unsigned short* __restrict__ e16,
    float* __restrict__ s2, int* __restrict__ count)
{
    const int tid = threadIdx.x;
    if (blockIdx.x == 0 && tid == 0) *count = 0;

    const int id = blockIdx.x * 256 + tid;
    const float* src = emb + (size_t)id * 8;
    float4 p0 = *reinterpret_cast<const float4*>(src);
    float4 p1 = *reinterpret_cast<const float4*>(src + 4);
    float fv[8] = {p0.x, p0.y, p0.z, p0.w, p1.x, p1.y, p1.z, p1.w};
    u16x8 vh;
    #pragma unroll
    for (int e = 0; e < 8; ++e) {
        _Float16 h = (_Float16)(fv[e] * 1024.0f);
        vh[e] = __builtin_bit_cast(unsigned short, h);
    }
    *reinterpret_cast<u16x8*>(e16 + (size_t)id * 8) = vh;

    if (tid < 8) {
        const int c = blockIdx.x * 8 + tid;
        const float* e = emb + (size_t)c * DDIM;
        s2[c] = block128_sq(e) + block128_sq(e + 128);
    }
}

// ---------------------------- pass 1 (fp16 MFMA, r10-r12 verbatim) ----------------------------
__global__ __launch_bounds__(256, 2) void vq_pass1(
    const float* __restrict__ z, const unsigned short* __restrict__ e16,
    const float* __restrict__ s2g, int* __restrict__ out,
    int* __restrict__ count, int* __restrict__ list, int N)
{
    __shared__ __align__(16) unsigned short Bt[2][2][4096];
    __shared__ float s2s[KCODES];
    __shared__ float Lbv[2][64], Lsv[2][64];
    __shared__ int   Lbk[2][64];

    const int tid  = threadIdx.x;
    const int wid  = tid >> 6, lane = tid & 63;
    const int ll   = lane & 15, lg = lane >> 4;
    const int rowHalf  = wid & 1, codeHalf = wid >> 1;
    const int rowbase  = blockIdx.x * 64 + rowHalf * 32;
    const int chbase   = codeHalf * 512;

    for (int c = tid; c < KCODES; c += 256) s2s[c] = s2g[c];

    const int sB     = (ll >> 1) & 3;
    const int rdbase = ll * 32 + ((lg ^ sB) << 3);

    f16x8  afrag[8][2];
    f32x4  acc[2][8];
    float  bv[2][4], sv[2][4];
    int    bk[2][4];
    #pragma unroll
    for (int m = 0; m < 2; ++m)
        #pragma unroll
        for (int j = 0; j < 4; ++j) { bv[m][j] = 3.4e38f; sv[m][j] = 3.4e38f; bk[m][j] = 0; }

    {
        #pragma unroll
        for (int q = 0; q < 4; ++q) {
            int id = q * 256 + tid;
            int half = id >> 9, rem = id & 511, cl = rem >> 2, pc = rem & 3;
            int clog = pc ^ ((cl >> 1) & 3);
            u16x8 v = *reinterpret_cast<const u16x8*>(
                e16 + (size_t)(half * 512 + cl) * DDIM + clog * 8);
            *reinterpret_cast<u16x8*>(&Bt[0][half][cl * 32 + pc * 8]) = v;
        }
    }
    __syncthreads();

    for (int ct = 0; ct < 4; ++ct) {
        const f32x4 zero4 = {0.f, 0.f, 0.f, 0.f};
        #pragma unroll
        for (int m = 0; m < 2; ++m)
            #pragma unroll
            for (int n = 0; n < 8; ++n) acc[m][n] = zero4;

        #pragma unroll
        for (int ks = 0; ks < 8; ++ks) {
            const int buf = ks & 1;
            const int t   = ct * 8 + ks;
            const bool hasNext = (t < 31);

            u16x8 sb[4];
            if (hasNext) {
                const int nt = t + 1, nct = nt >> 3, nks = nt & 7;
                #pragma unroll
                for (int q = 0; q < 4; ++q) {
                    int id = q * 256 + tid;
                    int half = id >> 9, rem = id & 511, cl = rem >> 2, pc = rem & 3;
                    int clog = pc ^ ((cl >> 1) & 3);
                    sb[q] = *reinterpret_cast<const u16x8*>(
                        e16 + (size_t)(half * 512 + nct * 128 + cl) * DDIM + nks * 32 + clog * 8);
                }
            }

            if (ct == 0) {
                #pragma unroll
                for (int m = 0; m < 2; ++m) {
                    const float* zp = z + (size_t)(rowbase + 16 * m + ll) * DDIM + ks * 32 + lg * 8;
                    float4 p0 = *reinterpret_cast<const float4*>(zp);
                    float4 p1 = *reinterpret_cast<const float4*>(zp + 4);
                    float fv[8] = {p0.x, p0.y, p0.z, p0.w, p1.x, p1.y, p1.z, p1.w};
                    #pragma unroll
                    for (int e = 0; e < 8; ++e) afrag[ks][m][e] = (_Float16)fv[e];
                }
            }

            #pragma unroll
            for (int n = 0; n < 8; ++n) {
                f16x8 bh = *reinterpret_cast<const f16x8*>(
                    &Bt[buf][codeHalf][n * 512 + rdbase]);
                #pragma unroll
                for (int m = 0; m < 2; ++m)
                    acc[m][n] = __builtin_amdgcn_mfma_f32_16x16x32_f16(
                        afrag[ks][m], bh, acc[m][n], 0, 0, 0);
            }

            if (ks == 7) {
                #pragma unroll
                for (int n = 0; n < 8; ++n) {
                    const int c = chbase + ct * 128 + n * 16 + ll;
                    const float s2v = s2s[c];
                    #pragma unroll
                    for (int m = 0; m < 2; ++m)
                        #pragma unroll
                        for (int j = 0; j < 4; ++j) {
                            float v = fmaf(-0.001953125f, acc[m][n][j], s2v);
                            if (v < bv[m][j] || (v == bv[m][j] && c < bk[m][j])) {
                                sv[m][j] = bv[m][j]; bv[m][j] = v; bk[m][j] = c;
                            } else {
                                sv[m][j] = fminf(sv[m][j], v);
                            }
                        }
                }
            }

            if (hasNext) {
                const int nbuf = buf ^ 1;
                #pragma unroll
                for (int q = 0; q < 4; ++q) {
                    int id = q * 256 + tid;
                    int half = id >> 9, rem = id & 511, cl = rem >> 2, pc = rem & 3;
                    *reinterpret_cast<u16x8*>(&Bt[nbuf][half][cl * 32 + pc * 8]) = sb[q];
                }
            }
            __syncthreads();
        }
    }

    #pragma unroll
    for (int off = 1; off < 16; off <<= 1) {
        #pragma unroll
        for (int m = 0; m < 2; ++m)
            #pragma unroll
            for (int j = 0; j < 4; ++j) {
                float ob = __shfl_xor(bv[m][j], off, 64);
                int   ok = __shfl_xor(bk[m][j], off, 64);
                float os = __shfl_xor(sv[m][j], off, 64);
                if (ob < bv[m][j] || (ob == bv[m][j] && ok < bk[m][j])) {
                    sv[m][j] = fminf(bv[m][j], os); bv[m][j] = ob; bk[m][j] = ok;
                } else {
                    sv[m][j] = fminf(sv[m][j], ob);
                }
            }
    }

    if (ll == 0) {
        #pragma unroll
        for (int m = 0; m < 2; ++m)
            #pragma unroll
            for (int j = 0; j < 4; ++j) {
                int rib = rowHalf * 32 + 16 * m + lg * 4 + j;
                Lbv[codeHalf][rib] = bv[m][j];
                Lsv[codeHalf][rib] = sv[m][j];
                Lbk[codeHalf][rib] = bk[m][j];
            }
    }
    __syncthreads();

    if (tid < 64) {
        const int r = blockIdx.x * 64 + tid;
        if (r < N) {
            float b0 = Lbv[0][tid], s0 = Lsv[0][tid]; int k0 = Lbk[0][tid];
            float b1 = Lbv[1][tid], s1 = Lsv[1][tid]; int k1 = Lbk[1][tid];
            float bb, ss; int kk;
            if (b1 < b0) { bb = b1; kk = k1; ss = fminf(s1, b0); }
            else         { bb = b0; kk = k0; ss = fminf(s0, b1); }
            out[r] = kk;
            if (ss - bb <= TAU) {
                int pos = atomicAdd(count, 1);
                if (pos < LISTCAP) list[pos] = r;
            }
        }
    }
}

// ------- pass 2: block-per-row fp16 scan + exact window (LOCKED recipe) -------
__global__ __launch_bounds__(256) void vq_pass2(
    const float* __restrict__ z, const float* __restrict__ emb,
    const unsigned short* __restrict__ e16, const float* __restrict__ s2g,
    const int* __restrict__ count, const int* __restrict__ list,
    int* __restrict__ out)
{
#pragma clang fp contract(off)
    __shared__ __align__(16) float zls[DDIM];   // 1 KB fp32 z row
    __shared__ float vls[KCODES];               // 4 KB scan values
    __shared__ float s2s[KCODES];               // 4 KB
    __shared__ float s1sh, bvsh;
    __shared__ float wmin[4];
    __shared__ int   candc[CANDCAP];
    __shared__ float cand_v[CANDCAP];
    __shared__ int   ncand;

    const int tid  = threadIdx.x;
    const int wv   = tid >> 6, lane = tid & 63;
    const int cslot = lane >> 2;     // 0..15: code slot within iter
    const int sub   = lane & 3;      // dim quarter (64 dims each)

    int cnt = *count; if (cnt > LISTCAP) cnt = LISTCAP;
    if ((int)blockIdx.x >= cnt) return;

    for (int c = tid; c < KCODES; c += 256) s2s[c] = s2g[c];

    for (int idx = blockIdx.x; idx < cnt; idx += P2GRID) {
        const int row = list[idx];

        if (tid < 64)
            *reinterpret_cast<float4*>(&zls[tid * 4]) =
                *reinterpret_cast<const float4*>(z + (size_t)row * DDIM + tid * 4);
        if (tid == 65) ncand = 0;    // distinct thread, same barrier covers
        __syncthreads();             // zls + ncand + s2s ready

        if (tid == 0) s1sh = block128_sq(zls) + block128_sq(zls + 128);

        // per-lane fp16 z fragment: dims sub*64 .. +63 (32 h2 pairs)
        h2 z16[32];
        {
            const float2* zp2 = reinterpret_cast<const float2*>(&zls[sub * 64]);
            #pragma unroll
            for (int q = 0; q < 32; ++q) {
                float2 f = zp2[q];
                h2 a; a[0] = (_Float16)f.x; a[1] = (_Float16)f.y;
                z16[q] = a;
            }
        }

        // ---- scan: wave wv covers codes wv*256 + i*16 + cslot ----
        for (int i = 0; i < 16; ++i) {
            const int c = wv * 256 + i * 16 + cslot;
            const f16x8* ep = reinterpret_cast<const f16x8*>(
                e16 + (size_t)c * DDIM + sub * 64);
            f16x8 ev[8];                          // ALL 64 halfs (r13 fix)
            #pragma unroll
            for (int qq = 0; qq < 8; ++qq) ev[qq] = ep[qq];

            float p = 0.f;
            #pragma unroll
            for (int q = 0; q < 32; ++q) {        // static q -> static indices
                h2 a;
                a[0] = ev[q >> 2][(q & 3) * 2];
                a[1] = ev[q >> 2][(q & 3) * 2 + 1];
#if __has_builtin(__builtin_amdgcn_fdot2)
                p = __builtin_amdgcn_fdot2(a, z16[q], p, false);
#else
                p = fmaf((float)a[0], (float)z16[q][0], p);
                p = fmaf((float)a[1], (float)z16[q][1], p);
#endif
            }
            p += __shfl_xor(p, 1, 64);            // 2-deep reduce over sub
            p += __shfl_xor(p, 2, 64);
            if (sub == 0)
                vls[c] = fmaf(-0.001953125f, p, s2s[c]);   // v = s2 - dot'/512
        }
        __syncthreads();

        // ---- block-wide min of vls ----
        float m = 3.4e38f;
        #pragma unroll
        for (int k = 0; k < 4; ++k) m = fminf(m, vls[tid + 256 * k]);
        #pragma unroll
        for (int off = 1; off < 64; off <<= 1) m = fminf(m, __shfl_xor(m, off, 64));
        if (lane == 0) wmin[wv] = m;
        __syncthreads();
        if (tid == 0)
            bvsh = fminf(fminf(wmin[0], wmin[1]), fminf(wmin[2], wmin[3]));
        __syncthreads();

        // ---- candidates: v <= bv + WIN ----
        const float thr = bvsh + WIN;
        #pragma unroll
        for (int k = 0; k < 4; ++k) {
            int c = tid + 256 * k;
            if (vls[c] <= thr) {
                int p = atomicAdd(&ncand, 1);
                if (p < CANDCAP) candc[p] = c;
            }
        }
        __syncthreads();
        int nc2 = ncand; if (nc2 > CANDCAP) nc2 = CANDCAP;
        const float s1 = s1sh;

        // ---- LOCKED exact recipe per candidate (one wave each) ----
        for (int i = wv; i < nc2; i += 4) {
            const int c = candc[i];
            float4 ev4 = *reinterpret_cast<const float4*>(emb + (size_t)c * DDIM + lane * 4);
            const float* zq = &zls[lane * 4];
            double ds = (double)zq[0] * (double)ev4.x;
            ds = fma((double)zq[1], (double)ev4.y, ds);
            ds = fma((double)zq[2], (double)ev4.z, ds);
            ds = fma((double)zq[3], (double)ev4.w, ds);
            #pragma unroll
            for (int off = 1; off < 64; off <<= 1)
                ds += __shfl_xor(ds, off, 64);           // exact fp64, order-free
            if (lane == 0) {
                float twog = 2.0f * (float)ds;           // LOCKED: fl32(2G)
                float t1   = s1 - twog;                  // fp32 rounding 1
                cand_v[i]  = t1 + s2s[c];                // fp32 rounding 2
            }
        }
        __syncthreads();

        if (tid == 0) {                                  // first-index argmin
            float bb = 3.4e38f; int kb = KCODES - 1;
            for (int i = 0; i < nc2; ++i) {
                float dv = cand_v[i]; int c = candc[i];
                if (dv < bb || (dv == bb && c < kb)) { bb = dv; kb = c; }
            }
            out[row] = kb;
        }
        __syncthreads();                                 // protect LDS for next row
    }
}

extern "C" void kernel_launch(void* const* d_in, const int* in_sizes, int n_in,
                              void* d_out, int out_size, void* d_ws, size_t ws_size,
                              hipStream_t stream) {
    const float* z   = (const float*)d_in[0];
    const float* emb = (const float*)d_in[1];
    int*   out   = (int*)d_out;
    float* s2    = (float*)d_ws;                                   // 4 KB
    int*   count = (int*)((char*)d_ws + 4096);
    int*   list  = (int*)((char*)d_ws + 4224);                     // 64 KB
    unsigned short* e16 = (unsigned short*)((char*)d_ws + 131072); // 512 KB
    const int N = in_sizes[0] / DDIM;                              // 32768

    vq_prep<<<dim3(128), dim3(256), 0, stream>>>(emb, e16, s2, count);
    vq_pass1<<<dim3(N / 64), dim3(256), 0, stream>>>(z, e16, s2, out, count, list, N);
    vq_pass2<<<dim3(P2GRID), dim3(256), 0, stream>>>(z, emb, e16, s2, count, list, out);
}

// Round 14
// 113.899 us; speedup vs baseline: 1.9725x; 1.9725x over previous
//
#include <hip/hip_runtime.h>

// VQ nearest-codebook argmin — fp16 MFMA pass-1 + block-per-row rescore.
//
// Pass 1 (validated r8-r13): G ≈ z16 . fp16(1024 e) / 1024, one f16 MFMA pass.
//   Rows with top-2 gap <= TAU=1.6e-4 -> list.
// Pass 2 (validated r13, absmax 0): ONE 256-THREAD BLOCK per flagged row.
//   fp16 dot2 scan (4 lanes/code, 64 dims/lane), candidates = v <= bv + WIN.
//   LOCKED numpy-fp32 recipe per candidate (rounds 3-13): s1,s2 numpy-pairwise
//   fp32 sums of squares; G exact-fp64 (order-free) -> fl32(2G);
//   d = fl32(fl32(s1-2G)+s2); argmin, first-index tie-break.
// r14 vs r13: SPILL FIX ONLY. r13 hit VGPR=256 + 107MB scratch FETCH (compiler
//   unrolled/hoisted the 16-iter scan -> ~128 loads in flight). Now:
//   __launch_bounds__(256,4) caps VGPR at 128; #pragma unroll 1 on the scan
//   loop; e-row loaded in 2 batches of 4 f16x8. Numerics bit-identical.

#define DDIM 256
#define KCODES 1024
#define TAU 1.6e-4f
#define WIN 1.2e-4f
#define LISTCAP 16384
#define CANDCAP 16
#define P2GRID 2048

typedef __attribute__((ext_vector_type(8))) _Float16 f16x8;
typedef __attribute__((ext_vector_type(2))) _Float16 h2;
typedef __attribute__((ext_vector_type(4))) float f32x4;
typedef __attribute__((ext_vector_type(8))) unsigned short u16x8;

// ---------- locked numerics helper (rounds 3-13, do not touch) ----------
__device__ __forceinline__ float block128_sq(const float* __restrict__ a)
{
#pragma clang fp contract(off)
    float r[8];
    #pragma unroll
    for (int j = 0; j < 8; ++j) { float v = a[j]; r[j] = v * v; }
    #pragma unroll
    for (int i = 8; i < 128; i += 8) {
        #pragma unroll
        for (int j = 0; j < 8; ++j) { float v = a[i + j]; r[j] = r[j] + v * v; }
    }
    return ((r[0] + r[1]) + (r[2] + r[3])) + ((r[4] + r[5]) + (r[6] + r[7]));
}

// ---- prep: e16 = fp16(1024*e), s2 pairwise, count reset (r9-validated) ----
__global__ __launch_bounds__(256) void vq_prep(
    const float* __restrict__ emb, unsigned short* __restrict__ e16,
    float* __restrict__ s2, int* __restrict__ count)
{
    const int tid = threadIdx.x;
    if (blockIdx.x == 0 && tid == 0) *count = 0;

    const int id = blockIdx.x * 256 + tid;
    const float* src = emb + (size_t)id * 8;
    float4 p0 = *reinterpret_cast<const float4*>(src);
    float4 p1 = *reinterpret_cast<const float4*>(src + 4);
    float fv[8] = {p0.x, p0.y, p0.z, p0.w, p1.x, p1.y, p1.z, p1.w};
    u16x8 vh;
    #pragma unroll
    for (int e = 0; e < 8; ++e) {
        _Float16 h = (_Float16)(fv[e] * 1024.0f);
        vh[e] = __builtin_bit_cast(unsigned short, h);
    }
    *reinterpret_cast<u16x8*>(e16 + (size_t)id * 8) = vh;

    if (tid < 8) {
        const int c = blockIdx.x * 8 + tid;
        const float* e = emb + (size_t)c * DDIM;
        s2[c] = block128_sq(e) + block128_sq(e + 128);
    }
}

// ---------------------------- pass 1 (fp16 MFMA, r10-r13 verbatim) ----------------------------
__global__ __launch_bounds__(256, 2) void vq_pass1(
    const float* __restrict__ z, const unsigned short* __restrict__ e16,
    const float* __restrict__ s2g, int* __restrict__ out,
    int* __restrict__ count, int* __restrict__ list, int N)
{
    __shared__ __align__(16) unsigned short Bt[2][2][4096];
    __shared__ float s2s[KCODES];
    __shared__ float Lbv[2][64], Lsv[2][64];
    __shared__ int   Lbk[2][64];

    const int tid  = threadIdx.x;
    const int wid  = tid >> 6, lane = tid & 63;
    const int ll   = lane & 15, lg = lane >> 4;
    const int rowHalf  = wid & 1, codeHalf = wid >> 1;
    const int rowbase  = blockIdx.x * 64 + rowHalf * 32;
    const int chbase   = codeHalf * 512;

    for (int c = tid; c < KCODES; c += 256) s2s[c] = s2g[c];

    const int sB     = (ll >> 1) & 3;
    const int rdbase = ll * 32 + ((lg ^ sB) << 3);

    f16x8  afrag[8][2];
    f32x4  acc[2][8];
    float  bv[2][4], sv[2][4];
    int    bk[2][4];
    #pragma unroll
    for (int m = 0; m < 2; ++m)
        #pragma unroll
        for (int j = 0; j < 4; ++j) { bv[m][j] = 3.4e38f; sv[m][j] = 3.4e38f; bk[m][j] = 0; }

    {
        #pragma unroll
        for (int q = 0; q < 4; ++q) {
            int id = q * 256 + tid;
            int half = id >> 9, rem = id & 511, cl = rem >> 2, pc = rem & 3;
            int clog = pc ^ ((cl >> 1) & 3);
            u16x8 v = *reinterpret_cast<const u16x8*>(
                e16 + (size_t)(half * 512 + cl) * DDIM + clog * 8);
            *reinterpret_cast<u16x8*>(&Bt[0][half][cl * 32 + pc * 8]) = v;
        }
    }
    __syncthreads();

    for (int ct = 0; ct < 4; ++ct) {
        const f32x4 zero4 = {0.f, 0.f, 0.f, 0.f};
        #pragma unroll
        for (int m = 0; m < 2; ++m)
            #pragma unroll
            for (int n = 0; n < 8; ++n) acc[m][n] = zero4;

        #pragma unroll
        for (int ks = 0; ks < 8; ++ks) {
            const int buf = ks & 1;
            const int t   = ct * 8 + ks;
            const bool hasNext = (t < 31);

            u16x8 sb[4];
            if (hasNext) {
                const int nt = t + 1, nct = nt >> 3, nks = nt & 7;
                #pragma unroll
                for (int q = 0; q < 4; ++q) {
                    int id = q * 256 + tid;
                    int half = id >> 9, rem = id & 511, cl = rem >> 2, pc = rem & 3;
                    int clog = pc ^ ((cl >> 1) & 3);
                    sb[q] = *reinterpret_cast<const u16x8*>(
                        e16 + (size_t)(half * 512 + nct * 128 + cl) * DDIM + nks * 32 + clog * 8);
                }
            }

            if (ct == 0) {
                #pragma unroll
                for (int m = 0; m < 2; ++m) {
                    const float* zp = z + (size_t)(rowbase + 16 * m + ll) * DDIM + ks * 32 + lg * 8;
                    float4 p0 = *reinterpret_cast<const float4*>(zp);
                    float4 p1 = *reinterpret_cast<const float4*>(zp + 4);
                    float fv[8] = {p0.x, p0.y, p0.z, p0.w, p1.x, p1.y, p1.z, p1.w};
                    #pragma unroll
                    for (int e = 0; e < 8; ++e) afrag[ks][m][e] = (_Float16)fv[e];
                }
            }

            #pragma unroll
            for (int n = 0; n < 8; ++n) {
                f16x8 bh = *reinterpret_cast<const f16x8*>(
                    &Bt[buf][codeHalf][n * 512 + rdbase]);
                #pragma unroll
                for (int m = 0; m < 2; ++m)
                    acc[m][n] = __builtin_amdgcn_mfma_f32_16x16x32_f16(
                        afrag[ks][m], bh, acc[m][n], 0, 0, 0);
            }

            if (ks == 7) {
                #pragma unroll
                for (int n = 0; n < 8; ++n) {
                    const int c = chbase + ct * 128 + n * 16 + ll;
                    const float s2v = s2s[c];
                    #pragma unroll
                    for (int m = 0; m < 2; ++m)
                        #pragma unroll
                        for (int j = 0; j < 4; ++j) {
                            float v = fmaf(-0.001953125f, acc[m][n][j], s2v);
                            if (v < bv[m][j] || (v == bv[m][j] && c < bk[m][j])) {
                                sv[m][j] = bv[m][j]; bv[m][j] = v; bk[m][j] = c;
                            } else {
                                sv[m][j] = fminf(sv[m][j], v);
                            }
                        }
                }
            }

            if (hasNext) {
                const int nbuf = buf ^ 1;
                #pragma unroll
                for (int q = 0; q < 4; ++q) {
                    int id = q * 256 + tid;
                    int half = id >> 9, rem = id & 511, cl = rem >> 2, pc = rem & 3;
                    *reinterpret_cast<u16x8*>(&Bt[nbuf][half][cl * 32 + pc * 8]) = sb[q];
                }
            }
            __syncthreads();
        }
    }

    #pragma unroll
    for (int off = 1; off < 16; off <<= 1) {
        #pragma unroll
        for (int m = 0; m < 2; ++m)
            #pragma unroll
            for (int j = 0; j < 4; ++j) {
                float ob = __shfl_xor(bv[m][j], off, 64);
                int   ok = __shfl_xor(bk[m][j], off, 64);
                float os = __shfl_xor(sv[m][j], off, 64);
                if (ob < bv[m][j] || (ob == bv[m][j] && ok < bk[m][j])) {
                    sv[m][j] = fminf(bv[m][j], os); bv[m][j] = ob; bk[m][j] = ok;
                } else {
                    sv[m][j] = fminf(sv[m][j], ob);
                }
            }
    }

    if (ll == 0) {
        #pragma unroll
        for (int m = 0; m < 2; ++m)
            #pragma unroll
            for (int j = 0; j < 4; ++j) {
                int rib = rowHalf * 32 + 16 * m + lg * 4 + j;
                Lbv[codeHalf][rib] = bv[m][j];
                Lsv[codeHalf][rib] = sv[m][j];
                Lbk[codeHalf][rib] = bk[m][j];
            }
    }
    __syncthreads();

    if (tid < 64) {
        const int r = blockIdx.x * 64 + tid;
        if (r < N) {
            float b0 = Lbv[0][tid], s0 = Lsv[0][tid]; int k0 = Lbk[0][tid];
            float b1 = Lbv[1][tid], s1 = Lsv[1][tid]; int k1 = Lbk[1][tid];
            float bb, ss; int kk;
            if (b1 < b0) { bb = b1; kk = k1; ss = fminf(s1, b0); }
            else         { bb = b0; kk = k0; ss = fminf(s0, b1); }
            out[r] = kk;
            if (ss - bb <= TAU) {
                int pos = atomicAdd(count, 1);
                if (pos < LISTCAP) list[pos] = r;
            }
        }
    }
}

// ------- pass 2: block-per-row fp16 scan + exact window (LOCKED recipe) -------
__global__ __launch_bounds__(256, 4) void vq_pass2(     // r14: cap VGPR at 128
    const float* __restrict__ z, const float* __restrict__ emb,
    const unsigned short* __restrict__ e16, const float* __restrict__ s2g,
    const int* __restrict__ count, const int* __restrict__ list,
    int* __restrict__ out)
{
#pragma clang fp contract(off)
    __shared__ __align__(16) float zls[DDIM];   // 1 KB fp32 z row
    __shared__ float vls[KCODES];               // 4 KB scan values
    __shared__ float s2s[KCODES];               // 4 KB
    __shared__ float s1sh, bvsh;
    __shared__ float wmin[4];
    __shared__ int   candc[CANDCAP];
    __shared__ float cand_v[CANDCAP];
    __shared__ int   ncand;

    const int tid  = threadIdx.x;
    const int wv   = tid >> 6, lane = tid & 63;
    const int cslot = lane >> 2;     // 0..15: code slot within iter
    const int sub   = lane & 3;      // dim quarter (64 dims each)

    int cnt = *count; if (cnt > LISTCAP) cnt = LISTCAP;
    if ((int)blockIdx.x >= cnt) return;

    for (int c = tid; c < KCODES; c += 256) s2s[c] = s2g[c];

    for (int idx = blockIdx.x; idx < cnt; idx += P2GRID) {
        const int row = list[idx];

        if (tid < 64)
            *reinterpret_cast<float4*>(&zls[tid * 4]) =
                *reinterpret_cast<const float4*>(z + (size_t)row * DDIM + tid * 4);
        if (tid == 65) ncand = 0;    // distinct thread, same barrier covers
        __syncthreads();             // zls + ncand + s2s ready

        if (tid == 0) s1sh = block128_sq(zls) + block128_sq(zls + 128);

        // per-lane fp16 z fragment: dims sub*64 .. +63 (32 h2 pairs)
        h2 z16[32];
        {
            const float2* zp2 = reinterpret_cast<const float2*>(&zls[sub * 64]);
            #pragma unroll
            for (int q = 0; q < 32; ++q) {
                float2 f = zp2[q];
                h2 a; a[0] = (_Float16)f.x; a[1] = (_Float16)f.y;
                z16[q] = a;
            }
        }

        // ---- scan: wave wv covers codes wv*256 + i*16 + cslot ----
        #pragma unroll 1                          // r14: forbid unroll/hoist blowup
        for (int i = 0; i < 16; ++i) {
            const int c = wv * 256 + i * 16 + cslot;
            const f16x8* ep = reinterpret_cast<const f16x8*>(
                e16 + (size_t)c * DDIM + sub * 64);

            float p = 0.f;
            #pragma unroll                         // r14: 2 batches of 4 f16x8
            for (int h = 0; h < 2; ++h) {
                f16x8 e0 = ep[4 * h + 0], e1 = ep[4 * h + 1];
                f16x8 e2 = ep[4 * h + 2], e3 = ep[4 * h + 3];
                #pragma unroll
                for (int q = 0; q < 4; ++q) {      // static indices throughout
                    h2 a0; a0[0] = e0[2 * q]; a0[1] = e0[2 * q + 1];
                    h2 a1; a1[0] = e1[2 * q]; a1[1] = e1[2 * q + 1];
                    h2 a2; a2[0] = e2[2 * q]; a2[1] = e2[2 * q + 1];
                    h2 a3; a3[0] = e3[2 * q]; a3[1] = e3[2 * q + 1];
#if __has_builtin(__builtin_amdgcn_fdot2)
                    p = __builtin_amdgcn_fdot2(a0, z16[h * 16 + q],      p, false);
                    p = __builtin_amdgcn_fdot2(a1, z16[h * 16 + 4 + q],  p, false);
                    p = __builtin_amdgcn_fdot2(a2, z16[h * 16 + 8 + q],  p, false);
                    p = __builtin_amdgcn_fdot2(a3, z16[h * 16 + 12 + q], p, false);
#else
                    p = fmaf((float)a0[0], (float)z16[h * 16 + q][0], p);
                    p = fmaf((float)a0[1], (float)z16[h * 16 + q][1], p);
                    p = fmaf((float)a1[0], (float)z16[h * 16 + 4 + q][0], p);
                    p = fmaf((float)a1[1], (float)z16[h * 16 + 4 + q][1], p);
                    p = fmaf((float)a2[0], (float)z16[h * 16 + 8 + q][0], p);
                    p = fmaf((float)a2[1], (float)z16[h * 16 + 8 + q][1], p);
                    p = fmaf((float)a3[0], (float)z16[h * 16 + 12 + q][0], p);
                    p = fmaf((float)a3[1], (float)z16[h * 16 + 12 + q][1], p);
#endif
                }
            }
            p += __shfl_xor(p, 1, 64);            // 2-deep reduce over sub
            p += __shfl_xor(p, 2, 64);
            if (sub == 0)
                vls[c] = fmaf(-0.001953125f, p, s2s[c]);   // v = s2 - dot'/512
        }
        __syncthreads();

        // ---- block-wide min of vls ----
        float m = 3.4e38f;
        #pragma unroll
        for (int k = 0; k < 4; ++k) m = fminf(m, vls[tid + 256 * k]);
        #pragma unroll
        for (int off = 1; off < 64; off <<= 1) m = fminf(m, __shfl_xor(m, off, 64));
        if (lane == 0) wmin[wv] = m;
        __syncthreads();
        if (tid == 0)
            bvsh = fminf(fminf(wmin[0], wmin[1]), fminf(wmin[2], wmin[3]));
        __syncthreads();

        // ---- candidates: v <= bv + WIN ----
        const float thr = bvsh + WIN;
        #pragma unroll
        for (int k = 0; k < 4; ++k) {
            int c = tid + 256 * k;
            if (vls[c] <= thr) {
                int p = atomicAdd(&ncand, 1);
                if (p < CANDCAP) candc[p] = c;
            }
        }
        __syncthreads();
        int nc2 = ncand; if (nc2 > CANDCAP) nc2 = CANDCAP;
        const float s1 = s1sh;

        // ---- LOCKED exact recipe per candidate (one wave each) ----
        for (int i = wv; i < nc2; i += 4) {
            const int c = candc[i];
            float4 ev4 = *reinterpret_cast<const float4*>(emb + (size_t)c * DDIM + lane * 4);
            const float* zq = &zls[lane * 4];
            double ds = (double)zq[0] * (double)ev4.x;
            ds = fma((double)zq[1], (double)ev4.y, ds);
            ds = fma((double)zq[2], (double)ev4.z, ds);
            ds = fma((double)zq[3], (double)ev4.w, ds);
            #pragma unroll
            for (int off = 1; off < 64; off <<= 1)
                ds += __shfl_xor(ds, off, 64);           // exact fp64, order-free
            if (lane == 0) {
                float twog = 2.0f * (float)ds;           // LOCKED: fl32(2G)
                float t1   = s1 - twog;                  // fp32 rounding 1
                cand_v[i]  = t1 + s2s[c];                // fp32 rounding 2
            }
        }
        __syncthreads();

        if (tid == 0) {                                  // first-index argmin
            float bb = 3.4e38f; int kb = KCODES - 1;
            for (int i = 0; i < nc2; ++i) {
                float dv = cand_v[i]; int c = candc[i];
                if (dv < bb || (dv == bb && c < kb)) { bb = dv; kb = c; }
            }
            out[row] = kb;
        }
        __syncthreads();                                 // protect LDS for next row
    }
}

extern "C" void kernel_launch(void* const* d_in, const int* in_sizes, int n_in,
                              void* d_out, int out_size, void* d_ws, size_t ws_size,
                              hipStream_t stream) {
    const float* z   = (const float*)d_in[0];
    const float* emb = (const float*)d_in[1];
    int*   out   = (int*)d_out;
    float* s2    = (float*)d_ws;                                   // 4 KB
    int*   count = (int*)((char*)d_ws + 4096);
    int*   list  = (int*)((char*)d_ws + 4224);                     // 64 KB
    unsigned short* e16 = (unsigned short*)((char*)d_ws + 131072); // 512 KB
    const int N = in_sizes[0] / DDIM;                              // 32768

    vq_prep<<<dim3(128), dim3(256), 0, stream>>>(emb, e16, s2, count);
    vq_pass1<<<dim3(N / 64), dim3(256), 0, stream>>>(z, e16, s2, out, count, list, N);
    vq_pass2<<<dim3(P2GRID), dim3(256), 0, stream>>>(z, emb, e16, s2, count, list, out);
}

// Round 15
// 91.729 us; speedup vs baseline: 2.4493x; 1.2417x over previous
//
#include <hip/hip_runtime.h>

// VQ nearest-codebook argmin — fp16 MFMA pass-1 (BK=64) + block-per-row rescore.
//
// Pass 1 (math validated r8-r14): G ≈ z16 . fp16(1024 e) / 1024, one f16 MFMA
//   pass; rows with top-2 gap <= TAU=1.6e-4 -> list. r15: BK=64 (32 MFMA per
//   barrier, 16 barriers) — B tile stored as two copies of the r8-validated
//   0-conflict 32-k layout; per-acc MFMA order bit-identical to r14.
// Pass 2 (validated r13/r14, absmax 0): ONE 256-thread block per flagged row.
//   fp16 dot2 scan, candidates = v <= bv + WIN=1.2e-4, then LOCKED numpy-fp32
//   recipe per candidate (rounds 3-14): s1,s2 numpy-pairwise fp32 sums of
//   squares; G exact-fp64 (order-free) -> fl32(2G); d = fl32(fl32(s1-2G)+s2);
//   argmin, first-index tie-break. r15: scan loads line-coalesced (lane chunk
//   = q*64B + sub*16B -> 4 lanes per 64B line instead of 1).

#define DDIM 256
#define KCODES 1024
#define TAU 1.6e-4f
#define WIN 1.2e-4f
#define LISTCAP 16384
#define CANDCAP 16
#define P2GRID 2048

typedef __attribute__((ext_vector_type(8))) _Float16 f16x8;
typedef __attribute__((ext_vector_type(2))) _Float16 h2;
typedef __attribute__((ext_vector_type(4))) float f32x4;
typedef __attribute__((ext_vector_type(8))) unsigned short u16x8;

// ---------- locked numerics helper (rounds 3-14, do not touch) ----------
__device__ __forceinline__ float block128_sq(const float* __restrict__ a)
{
#pragma clang fp contract(off)
    float r[8];
    #pragma unroll
    for (int j = 0; j < 8; ++j) { float v = a[j]; r[j] = v * v; }
    #pragma unroll
    for (int i = 8; i < 128; i += 8) {
        #pragma unroll
        for (int j = 0; j < 8; ++j) { float v = a[i + j]; r[j] = r[j] + v * v; }
    }
    return ((r[0] + r[1]) + (r[2] + r[3])) + ((r[4] + r[5]) + (r[6] + r[7]));
}

// ---- prep: e16 = fp16(1024*e), s2 pairwise, count reset (r9-validated) ----
__global__ __launch_bounds__(256) void vq_prep(
    const float* __restrict__ emb, unsigned short* __restrict__ e16,
    float* __restrict__ s2, int* __restrict__ count)
{
    const int tid = threadIdx.x;
    if (blockIdx.x == 0 && tid == 0) *count = 0;

    const int id = blockIdx.x * 256 + tid;
    const float* src = emb + (size_t)id * 8;
    float4 p0 = *reinterpret_cast<const float4*>(src);
    float4 p1 = *reinterpret_cast<const float4*>(src + 4);
    float fv[8] = {p0.x, p0.y, p0.z, p0.w, p1.x, p1.y, p1.z, p1.w};
    u16x8 vh;
    #pragma unroll
    for (int e = 0; e < 8; ++e) {
        _Float16 h = (_Float16)(fv[e] * 1024.0f);
        vh[e] = __builtin_bit_cast(unsigned short, h);
    }
    *reinterpret_cast<u16x8*>(e16 + (size_t)id * 8) = vh;

    if (tid < 8) {
        const int c = blockIdx.x * 8 + tid;
        const float* e = emb + (size_t)c * DDIM;
        s2[c] = block128_sq(e) + block128_sq(e + 128);
    }
}

// ---------------------------- pass 1 (fp16 MFMA, BK=64) ----------------------------
__global__ __launch_bounds__(256, 2) void vq_pass1(
    const float* __restrict__ z, const unsigned short* __restrict__ e16,
    const float* __restrict__ s2g, int* __restrict__ out,
    int* __restrict__ count, int* __restrict__ list, int N)
{
    // [dbuf][ksub][codeHalf][128 codes x 32 halfs] — each ksub slab is the
    // r8-validated 0-conflict layout.
    __shared__ __align__(16) unsigned short Bt[2][2][2][4096];   // 64 KB
    __shared__ float s2s[KCODES];
    __shared__ float Lbv[2][64], Lsv[2][64];
    __shared__ int   Lbk[2][64];

    const int tid  = threadIdx.x;
    const int wid  = tid >> 6, lane = tid & 63;
    const int ll   = lane & 15, lg = lane >> 4;
    const int rowHalf  = wid & 1, codeHalf = wid >> 1;
    const int rowbase  = blockIdx.x * 64 + rowHalf * 32;
    const int chbase   = codeHalf * 512;

    for (int c = tid; c < KCODES; c += 256) s2s[c] = s2g[c];

    const int sB     = (ll >> 1) & 3;
    const int rdbase = ll * 32 + ((lg ^ sB) << 3);

    f16x8  afrag[8][2];
    f32x4  acc[2][8];
    float  bv[2][4], sv[2][4];
    int    bk[2][4];
    #pragma unroll
    for (int m = 0; m < 2; ++m)
        #pragma unroll
        for (int j = 0; j < 4; ++j) { bv[m][j] = 3.4e38f; sv[m][j] = 3.4e38f; bk[m][j] = 0; }

    // prologue: stage tile 0 (old-nt 0,1) into buf 0
    {
        #pragma unroll
        for (int q = 0; q < 8; ++q) {
            const int ksub = q >> 2, nt = ksub;          // nt = 2*0 + ksub
            int id = (q & 3) * 256 + tid;
            int half = id >> 9, rem = id & 511, cl = rem >> 2, pc = rem & 3;
            int clog = pc ^ ((cl >> 1) & 3);
            u16x8 v = *reinterpret_cast<const u16x8*>(
                e16 + (size_t)(half * 512 + (nt >> 3) * 128 + cl) * DDIM
                    + (nt & 7) * 32 + clog * 8);
            *reinterpret_cast<u16x8*>(&Bt[0][ksub][half][cl * 32 + pc * 8]) = v;
        }
    }
    __syncthreads();

    for (int t = 0; t < 16; ++t) {                       // 16 tiles of BK=64
        const int buf = t & 1;
        const int ct  = t >> 2;
        const bool hasNext = (t < 15);

        u16x8 sb[8];
        if (hasNext) {
            #pragma unroll
            for (int q = 0; q < 8; ++q) {
                const int ksub = q >> 2, nt = 2 * (t + 1) + ksub;
                int id = (q & 3) * 256 + tid;
                int half = id >> 9, rem = id & 511, cl = rem >> 2, pc = rem & 3;
                int clog = pc ^ ((cl >> 1) & 3);
                sb[q] = *reinterpret_cast<const u16x8*>(
                    e16 + (size_t)(half * 512 + (nt >> 3) * 128 + cl) * DDIM
                        + (nt & 7) * 32 + clog * 8);
            }
        }

        if ((t & 3) == 0) {
            const f32x4 zero4 = {0.f, 0.f, 0.f, 0.f};
            #pragma unroll
            for (int m = 0; m < 2; ++m)
                #pragma unroll
                for (int n = 0; n < 8; ++n) acc[m][n] = zero4;
        }

        if (t < 4) {                 // ct==0: convert A frags for ks=2t, 2t+1
            #pragma unroll
            for (int ksub = 0; ksub < 2; ++ksub) {
                const int ks = 2 * t + ksub;
                #pragma unroll
                for (int m = 0; m < 2; ++m) {
                    const float* zp = z + (size_t)(rowbase + 16 * m + ll) * DDIM + ks * 32 + lg * 8;
                    float4 p0 = *reinterpret_cast<const float4*>(zp);
                    float4 p1 = *reinterpret_cast<const float4*>(zp + 4);
                    float fv[8] = {p0.x, p0.y, p0.z, p0.w, p1.x, p1.y, p1.z, p1.w};
                    #pragma unroll
                    for (int e = 0; e < 8; ++e) afrag[ks][m][e] = (_Float16)fv[e];
                }
            }
        }

        #pragma unroll
        for (int ksub = 0; ksub < 2; ++ksub) {           // 32 MFMA per barrier
            const int ks = ((t & 3) * 2 + ksub);         // afrag index within ct
            #pragma unroll
            for (int n = 0; n < 8; ++n) {
                f16x8 bh = *reinterpret_cast<const f16x8*>(
                    &Bt[buf][ksub][codeHalf][n * 512 + rdbase]);
                #pragma unroll
                for (int m = 0; m < 2; ++m)
                    acc[m][n] = __builtin_amdgcn_mfma_f32_16x16x32_f16(
                        afrag[ks][m], bh, acc[m][n], 0, 0, 0);
            }
        }

        if ((t & 3) == 3) {          // end of ct: fold into running top-2
            #pragma unroll
            for (int n = 0; n < 8; ++n) {
                const int c = chbase + ct * 128 + n * 16 + ll;
                const float s2v = s2s[c];
                #pragma unroll
                for (int m = 0; m < 2; ++m)
                    #pragma unroll
                    for (int j = 0; j < 4; ++j) {
                        float v = fmaf(-0.001953125f, acc[m][n][j], s2v);
                        if (v < bv[m][j] || (v == bv[m][j] && c < bk[m][j])) {
                            sv[m][j] = bv[m][j]; bv[m][j] = v; bk[m][j] = c;
                        } else {
                            sv[m][j] = fminf(sv[m][j], v);
                        }
                    }
            }
        }

        if (hasNext) {
            const int nbuf = buf ^ 1;
            #pragma unroll
            for (int q = 0; q < 8; ++q) {
                const int ksub = q >> 2;
                int id = (q & 3) * 256 + tid;
                int half = id >> 9, rem = id & 511, cl = rem >> 2, pc = rem & 3;
                *reinterpret_cast<u16x8*>(&Bt[nbuf][ksub][half][cl * 32 + pc * 8]) = sb[q];
            }
        }
        __syncthreads();
    }

    #pragma unroll
    for (int off = 1; off < 16; off <<= 1) {
        #pragma unroll
        for (int m = 0; m < 2; ++m)
            #pragma unroll
            for (int j = 0; j < 4; ++j) {
                float ob = __shfl_xor(bv[m][j], off, 64);
                int   ok = __shfl_xor(bk[m][j], off, 64);
                float os = __shfl_xor(sv[m][j], off, 64);
                if (ob < bv[m][j] || (ob == bv[m][j] && ok < bk[m][j])) {
                    sv[m][j] = fminf(bv[m][j], os); bv[m][j] = ob; bk[m][j] = ok;
                } else {
                    sv[m][j] = fminf(sv[m][j], ob);
                }
            }
    }

    if (ll == 0) {
        #pragma unroll
        for (int m = 0; m < 2; ++m)
            #pragma unroll
            for (int j = 0; j < 4; ++j) {
                int rib = rowHalf * 32 + 16 * m + lg * 4 + j;
                Lbv[codeHalf][rib] = bv[m][j];
                Lsv[codeHalf][rib] = sv[m][j];
                Lbk[codeHalf][rib] = bk[m][j];
            }
    }
    __syncthreads();

    if (tid < 64) {
        const int r = blockIdx.x * 64 + tid;
        if (r < N) {
            float b0 = Lbv[0][tid], s0 = Lsv[0][tid]; int k0 = Lbk[0][tid];
            float b1 = Lbv[1][tid], s1 = Lsv[1][tid]; int k1 = Lbk[1][tid];
            float bb, ss; int kk;
            if (b1 < b0) { bb = b1; kk = k1; ss = fminf(s1, b0); }
            else         { bb = b0; kk = k0; ss = fminf(s0, b1); }
            out[r] = kk;
            if (ss - bb <= TAU) {
                int pos = atomicAdd(count, 1);
                if (pos < LISTCAP) list[pos] = r;
            }
        }
    }
}

// ------- pass 2: block-per-row fp16 scan + exact window (LOCKED recipe) -------
__global__ __launch_bounds__(256, 4) void vq_pass2(
    const float* __restrict__ z, const float* __restrict__ emb,
    const unsigned short* __restrict__ e16, const float* __restrict__ s2g,
    const int* __restrict__ count, const int* __restrict__ list,
    int* __restrict__ out)
{
#pragma clang fp contract(off)
    __shared__ __align__(16) float zls[DDIM];   // 1 KB fp32 z row
    __shared__ float vls[KCODES];               // 4 KB scan values
    __shared__ float s2s[KCODES];               // 4 KB
    __shared__ float s1sh, bvsh;
    __shared__ float wmin[4];
    __shared__ int   candc[CANDCAP];
    __shared__ float cand_v[CANDCAP];
    __shared__ int   ncand;

    const int tid  = threadIdx.x;
    const int wv   = tid >> 6, lane = tid & 63;
    const int cslot = lane >> 2;     // 0..15: code slot within iter
    const int sub   = lane & 3;      // chunk class (interleaved 8-dim groups)

    int cnt = *count; if (cnt > LISTCAP) cnt = LISTCAP;
    if ((int)blockIdx.x >= cnt) return;

    for (int c = tid; c < KCODES; c += 256) s2s[c] = s2g[c];

    for (int idx = blockIdx.x; idx < cnt; idx += P2GRID) {
        const int row = list[idx];

        if (tid < 64)
            *reinterpret_cast<float4*>(&zls[tid * 4]) =
                *reinterpret_cast<const float4*>(z + (size_t)row * DDIM + tid * 4);
        if (tid == 65) ncand = 0;    // distinct thread, same barrier covers
        __syncthreads();             // zls + ncand + s2s ready

        if (tid == 0) s1sh = block128_sq(zls) + block128_sq(zls + 128);

        // per-lane fp16 z fragment: dims q*32 + sub*8 + {0..7}, q = 0..7
        // (r15: interleaved layout matching the coalesced e-chunk map)
        h2 z16[32];
        {
            const float2* zp2 = reinterpret_cast<const float2*>(&zls[0]);
            #pragma unroll
            for (int q = 0; q < 8; ++q)
                #pragma unroll
                for (int j = 0; j < 4; ++j) {
                    float2 f = zp2[q * 16 + sub * 4 + j];
                    h2 a; a[0] = (_Float16)f.x; a[1] = (_Float16)f.y;
                    z16[q * 4 + j] = a;
                }
        }

        // ---- scan: wave wv covers codes wv*256 + i*16 + cslot ----
        #pragma unroll 1                          // keep VGPR bounded (r14 lesson)
        for (int i = 0; i < 16; ++i) {
            const int c = wv * 256 + i * 16 + cslot;
            const unsigned short* base = e16 + (size_t)c * DDIM;

            float p = 0.f;
            #pragma unroll                         // 2 batches of 4 coalesced loads
            for (int h = 0; h < 2; ++h) {
                // load q = 4h+k: halfs [ (4h+k)*32 + sub*8 .. +7 ]
                f16x8 e0 = *reinterpret_cast<const f16x8*>(base + (4 * h + 0) * 32 + sub * 8);
                f16x8 e1 = *reinterpret_cast<const f16x8*>(base + (4 * h + 1) * 32 + sub * 8);
                f16x8 e2 = *reinterpret_cast<const f16x8*>(base + (4 * h + 2) * 32 + sub * 8);
                f16x8 e3 = *reinterpret_cast<const f16x8*>(base + (4 * h + 3) * 32 + sub * 8);
                #pragma unroll
                for (int j = 0; j < 4; ++j) {      // static indices throughout
                    h2 a0; a0[0] = e0[2 * j]; a0[1] = e0[2 * j + 1];
                    h2 a1; a1[0] = e1[2 * j]; a1[1] = e1[2 * j + 1];
                    h2 a2; a2[0] = e2[2 * j]; a2[1] = e2[2 * j + 1];
                    h2 a3; a3[0] = e3[2 * j]; a3[1] = e3[2 * j + 1];
#if __has_builtin(__builtin_amdgcn_fdot2)
                    p = __builtin_amdgcn_fdot2(a0, z16[(4 * h + 0) * 4 + j], p, false);
                    p = __builtin_amdgcn_fdot2(a1, z16[(4 * h + 1) * 4 + j], p, false);
                    p = __builtin_amdgcn_fdot2(a2, z16[(4 * h + 2) * 4 + j], p, false);
                    p = __builtin_amdgcn_fdot2(a3, z16[(4 * h + 3) * 4 + j], p, false);
#else
                    p = fmaf((float)a0[0], (float)z16[(4 * h + 0) * 4 + j][0], p);
                    p = fmaf((float)a0[1], (float)z16[(4 * h + 0) * 4 + j][1], p);
                    p = fmaf((float)a1[0], (float)z16[(4 * h + 1) * 4 + j][0], p);
                    p = fmaf((float)a1[1], (float)z16[(4 * h + 1) * 4 + j][1], p);
                    p = fmaf((float)a2[0], (float)z16[(4 * h + 2) * 4 + j][0], p);
                    p = fmaf((float)a2[1], (float)z16[(4 * h + 2) * 4 + j][1], p);
                    p = fmaf((float)a3[0], (float)z16[(4 * h + 3) * 4 + j][0], p);
                    p = fmaf((float)a3[1], (float)z16[(4 * h + 3) * 4 + j][1], p);
#endif
                }
            }
            p += __shfl_xor(p, 1, 64);            // 2-deep reduce over sub
            p += __shfl_xor(p, 2, 64);
            if (sub == 0)
                vls[c] = fmaf(-0.001953125f, p, s2s[c]);   // v = s2 - dot'/512
        }
        __syncthreads();

        // ---- block-wide min of vls ----
        float m = 3.4e38f;
        #pragma unroll
        for (int k = 0; k < 4; ++k) m = fminf(m, vls[tid + 256 * k]);
        #pragma unroll
        for (int off = 1; off < 64; off <<= 1) m = fminf(m, __shfl_xor(m, off, 64));
        if (lane == 0) wmin[wv] = m;
        __syncthreads();
        if (tid == 0)
            bvsh = fminf(fminf(wmin[0], wmin[1]), fminf(wmin[2], wmin[3]));
        __syncthreads();

        // ---- candidates: v <= bv + WIN ----
        const float thr = bvsh + WIN;
        #pragma unroll
        for (int k = 0; k < 4; ++k) {
            int c = tid + 256 * k;
            if (vls[c] <= thr) {
                int p = atomicAdd(&ncand, 1);
                if (p < CANDCAP) candc[p] = c;
            }
        }
        __syncthreads();
        int nc2 = ncand; if (nc2 > CANDCAP) nc2 = CANDCAP;
        const float s1 = s1sh;

        // ---- LOCKED exact recipe per candidate (one wave each) ----
        for (int i = wv; i < nc2; i += 4) {
            const int c = candc[i];
            float4 ev4 = *reinterpret_cast<const float4*>(emb + (size_t)c * DDIM + lane * 4);
            const float* zq = &zls[lane * 4];
            double ds = (double)zq[0] * (double)ev4.x;
            ds = fma((double)zq[1], (double)ev4.y, ds);
            ds = fma((double)zq[2], (double)ev4.z, ds);
            ds = fma((double)zq[3], (double)ev4.w, ds);
            #pragma unroll
            for (int off = 1; off < 64; off <<= 1)
                ds += __shfl_xor(ds, off, 64);           // exact fp64, order-free
            if (lane == 0) {
                float twog = 2.0f * (float)ds;           // LOCKED: fl32(2G)
                float t1   = s1 - twog;                  // fp32 rounding 1
                cand_v[i]  = t1 + s2s[c];                // fp32 rounding 2
            }
        }
        __syncthreads();

        if (tid == 0) {                                  // first-index argmin
            float bb = 3.4e38f; int kb = KCODES - 1;
            for (int i = 0; i < nc2; ++i) {
                float dv = cand_v[i]; int c = candc[i];
                if (dv < bb || (dv == bb && c < kb)) { bb = dv; kb = c; }
            }
            out[row] = kb;
        }
        __syncthreads();                                 // protect LDS for next row
    }
}

extern "C" void kernel_launch(void* const* d_in, const int* in_sizes, int n_in,
                              void* d_out, int out_size, void* d_ws, size_t ws_size,
                              hipStream_t stream) {
    const float* z   = (const float*)d_in[0];
    const float* emb = (const float*)d_in[1];
    int*   out   = (int*)d_out;
    float* s2    = (float*)d_ws;                                   // 4 KB
    int*   count = (int*)((char*)d_ws + 4096);
    int*   list  = (int*)((char*)d_ws + 4224);                     // 64 KB
    unsigned short* e16 = (unsigned short*)((char*)d_ws + 131072); // 512 KB
    const int N = in_sizes[0] / DDIM;                              // 32768

    vq_prep<<<dim3(128), dim3(256), 0, stream>>>(emb, e16, s2, count);
    vq_pass1<<<dim3(N / 64), dim3(256), 0, stream>>>(z, e16, s2, out, count, list, N);
    vq_pass2<<<dim3(P2GRID), dim3(256), 0, stream>>>(z, emb, e16, s2, count, list, out);
}